// Round 1
// 1062.383 us; speedup vs baseline: 1.0375x; 1.0375x over previous
//
#include <hip/hip_runtime.h>
#include <hip/hip_bf16.h>

// B=2 T=2048 D=2048 N=16 K=8 H=128 F=8192 G=2, M=B*T=4096
// FP32 I/O, bf16 MFMA internal. ws use: 176 MiB (proven safe).
// R6: all big GEMMs moved to an 8-wave BMx256 phased kernel (T1 XCD swizzle,
// T2 LDS XOR-swizzle via pre-swizzled gload_lds source, T3/T4 counted-vmcnt
// 1.5-K-tile lookahead with one barrier per quadrant-phase, T5 setprio).
// Gating un-fused: up-pass writes ACT, gate-pass RMWs gelu(g)*u in epilogue.

typedef __attribute__((ext_vector_type(8))) short bf16x8;
typedef __attribute__((ext_vector_type(4))) float f32x4;

#define GLP(p) ((const __attribute__((address_space(1))) void*)(p))
#define LDSP(p) ((__attribute__((address_space(3))) void*)(p))
#define FBAR() do { asm volatile("" ::: "memory"); __builtin_amdgcn_s_barrier(); asm volatile("" ::: "memory"); } while (0)

__device__ __forceinline__ float bf2f(unsigned short h) {
  union { unsigned int u; float f; } v; v.u = ((unsigned int)h) << 16; return v.f;
}
__device__ __forceinline__ unsigned short f2bf(float f) {
  union { float f; unsigned int u; } v; v.f = f;
  unsigned int r = v.u + 0x7fffu + ((v.u >> 16) & 1u);
  return (unsigned short)(r >> 16);
}
__device__ __forceinline__ float gelu_f(float x) {
  float t = tanhf(0.7978845608028654f * (x + 0.044715f * x * x * x));
  return 0.5f * x * (1.f + t);
}

// ---------------- RMSNorm: one block per row of D=2048. IN_F32: x is fp32 ----------------
template <int IN_F32>
__global__ __launch_bounds__(256) void rmsnorm_kernel(const void* __restrict__ x_,
                                                      const float* __restrict__ scale,
                                                      unsigned short* __restrict__ out) {
  int row = blockIdx.x, tid = threadIdx.x;
  float f[8]; float ss = 0.f;
  if (IN_F32) {
    const float* xr = (const float*)x_ + (size_t)row * 2048 + tid * 8;
#pragma unroll
    for (int i = 0; i < 8; ++i) { f[i] = xr[i]; ss += f[i] * f[i]; }
  } else {
    const unsigned short* xr = (const unsigned short*)x_ + (size_t)row * 2048;
    bf16x8 xv = *(const bf16x8*)(xr + tid * 8);
#pragma unroll
    for (int i = 0; i < 8; ++i) { f[i] = bf2f((unsigned short)xv[i]); ss += f[i] * f[i]; }
  }
#pragma unroll
  for (int off = 32; off >= 1; off >>= 1) ss += __shfl_xor(ss, off);
  __shared__ float red[4];
  if ((tid & 63) == 0) red[tid >> 6] = ss;
  __syncthreads();
  ss = red[0] + red[1] + red[2] + red[3];
  float r = rsqrtf(ss * (1.f / 2048.f) + 1e-6f);
  const float* sv = scale + tid * 8;
  bf16x8 o;
#pragma unroll
  for (int i = 0; i < 8; ++i) o[i] = (short)f2bf(f[i] * r * (1.f + sv[i]));
  *(bf16x8*)(out + (size_t)row * 2048 + tid * 8) = o;
}

// ------- batched 2D transpose + fp32->bf16 cast: in fp32 (R x ldi) -> out bf16 (cols x R) -------
__global__ __launch_bounds__(256) void transpose_cast_kernel(const float* __restrict__ in,
                                                             unsigned short* __restrict__ out,
                                                             int R, int ldi, long ibs, long obs) {
  __shared__ float tile[32][33];
  int z = blockIdx.z;
  const float* ip = in + (size_t)z * ibs;
  unsigned short* op = out + (size_t)z * obs;
  int c0 = blockIdx.x * 32, r0 = blockIdx.y * 32;
  int tx = threadIdx.x, ty = threadIdx.y;
#pragma unroll
  for (int i = 0; i < 32; i += 8)
    tile[ty + i][tx] = ip[(size_t)(r0 + ty + i) * ldi + (c0 + tx)];
  __syncthreads();
#pragma unroll
  for (int i = 0; i < 32; i += 8)
    op[(size_t)(c0 + ty + i) * R + (r0 + tx)] = f2bf(tile[tx][ty + i]);
}

// v part of qkv (bf16, cols 3072..4095) -> vT[(b*8+kh)*128 + h][s]
__global__ __launch_bounds__(256) void vtrans_kernel(const unsigned short* __restrict__ qkv,
                                                     unsigned short* __restrict__ vT) {
  __shared__ unsigned short tile[32][33];
  int z = blockIdx.z, bb = z >> 3, kh = z & 7;
  int s0 = blockIdx.x * 32, h0 = blockIdx.y * 32;
  int tx = threadIdx.x, ty = threadIdx.y;
  const unsigned short* ip = qkv + ((size_t)bb * 2048) * 4096 + 3072 + kh * 128;
  unsigned short* op = vT + (size_t)z * 128 * 2048;
#pragma unroll
  for (int i = 0; i < 32; i += 8)
    tile[ty + i][tx] = ip[(size_t)(s0 + ty + i) * 4096 + h0 + tx];
  __syncthreads();
#pragma unroll
  for (int i = 0; i < 32; i += 8)
    op[(size_t)(h0 + ty + i) * 2048 + s0 + tx] = tile[tx][ty + i];
}

// ---------------- 8-wave phased GEMM: C(M x Ncols) = A(M x Kd) * BT(Ncols x Kd)^T ----------------
// BM x 256 tile, BK=64, 512 threads (8 waves, 2M x 4N), per-wave BM/2 x 64 output.
// Per K-tile: 4 quadrant-phases (mhalf x nhalf), ONE barrier per phase.
// Staging schedule (half-tiles): Bn1(t+1)@P1, Am1(t+1)@P2, Am0(t+2)@P3, Bn0(t+2)@P4,
// then s_waitcnt vmcnt(4|3) (leaves {Am0(t+2),Bn0(t+2)} in flight; never 0 mid-loop).
// LDS rows permuted so each gload_lds 64-row chunk == one phase's consumption set:
//   A (BM=256): rho = (mh)*128 + wm*64 + ...   A (BM=128): rho = (mh)*64 + wm*32 + ...
//   B:          rho = (nh)*128 + wn*32 + ...
// Bank-conflict swizzle byte^=(row&7)<<4 applied via inverse-swizzled GLOBAL source
// (gload_lds LDS dest must stay linear) + swizzled ds_read address.
// MODE 0: bf16 out. MODE 1: v += add (ADD_F32 in-dtype; OUT_F32 out-dtype).
// MODE 2: out = f2bf(gelu(acc) * bf2f(out))  (gating: fuses gelu*up RMW).
template <int BM, int MODE, int OUT_F32, int ADD_F32>
__global__ __launch_bounds__(512, 2) void gemm8p(const unsigned short* __restrict__ A,
                                                 const unsigned short* __restrict__ BT,
                                                 int Kd, int ldc, int gx,
                                                 void* __restrict__ out_,
                                                 const void* __restrict__ add_) {
  constexpr int MR = BM / 32;   // A frags per wave (8 | 4)
  constexpr int MH = MR / 2;
  constexpr int ASZ = BM * 64;  // shorts per A K-tile buffer
  constexpr int BSZ = 256 * 64;
  __shared__ unsigned short lds[2 * ASZ + 2 * BSZ];
  unsigned short* aBuf0 = lds;
  unsigned short* aBuf1 = lds + ASZ;
  unsigned short* bBuf0 = lds + 2 * ASZ;
  unsigned short* bBuf1 = lds + 2 * ASZ + BSZ;

  int tid = threadIdx.x;
  int lane = tid & 63, w = tid >> 6;
  int quad = lane >> 4, l16 = lane & 15;
  int wm = w >> 2, wn = w & 3;
  int l8 = lane >> 3;

  // T1: bijective XCD swizzle over 1-D grid (nwg == 256, % 8 == 0)
  int nwg = gridDim.x;
  int id = blockIdx.x;
  int swzid = (id & 7) * (nwg >> 3) + (id >> 3);
  int bx = swzid % gx, by = swzid / gx;
  long rowBase = (long)by * BM, colBase = (long)bx * 256;

  // per-lane staging source (inverse-swizzled col; row via LDS-row permutation inverse)
  int csw = ((lane & 7) ^ l8) * 8;                      // swizzled col (shorts)
  int rwB = (w >> 2) * 64 + (w & 3) * 8 + l8;           // B: chunk-32 permutation
  int rwA = (BM == 256) ? (w * 8 + l8) : rwB;           // A: chunk-64 (256) / chunk-32 (128)
  const unsigned short* aSrc = A + (rowBase + rwA) * (size_t)Kd + csw;
  const unsigned short* bSrc = BT + (colBase + rwB) * (size_t)Kd + csw;

  auto stgA = [&](unsigned short* dst, int h, int tt) {
    if (BM == 256) {
      __builtin_amdgcn_global_load_lds(GLP(aSrc + (size_t)(h * 64) * Kd + (size_t)tt * 64),
                                       LDSP(dst + (h * 128 + w * 8) * 64), 16, 0, 0);
      __builtin_amdgcn_global_load_lds(GLP(aSrc + (size_t)(128 + h * 64) * Kd + (size_t)tt * 64),
                                       LDSP(dst + (h * 128 + 64 + w * 8) * 64), 16, 0, 0);
    } else {
      __builtin_amdgcn_global_load_lds(GLP(aSrc + (size_t)(h * 32) * Kd + (size_t)tt * 64),
                                       LDSP(dst + (h * 64 + w * 8) * 64), 16, 0, 0);
    }
  };
  auto stgB = [&](unsigned short* dst, int h, int tt) {
    __builtin_amdgcn_global_load_lds(GLP(bSrc + (size_t)(h * 32) * Kd + (size_t)tt * 64),
                                     LDSP(dst + (h * 128 + w * 8) * 64), 16, 0, 0);
    __builtin_amdgcn_global_load_lds(GLP(bSrc + (size_t)(128 + h * 32) * Kd + (size_t)tt * 64),
                                     LDSP(dst + (h * 128 + 64 + w * 8) * 64), 16, 0, 0);
  };

  int swq0 = (quad * 8) ^ ((l16 & 7) * 8);
  int swq1 = (32 + quad * 8) ^ ((l16 & 7) * 8);
  auto rdA = [&](const unsigned short* cur, int i, int kk) -> bf16x8 {
    int rho = (BM == 256) ? ((i >> 2) * 128 + wm * 64 + (i & 3) * 16 + l16)
                          : ((i >> 1) * 64 + wm * 32 + (i & 1) * 16 + l16);
    return *(const bf16x8*)(cur + rho * 64 + (kk ? swq1 : swq0));
  };
  auto rdB = [&](const unsigned short* cur, int j, int kk) -> bf16x8 {
    int rho = (j >> 1) * 128 + wn * 32 + (j & 1) * 16 + l16;
    return *(const bf16x8*)(cur + rho * 64 + (kk ? swq1 : swq0));
  };

  f32x4 acc[MR][4];
#pragma unroll
  for (int i = 0; i < MR; ++i)
#pragma unroll
    for (int j = 0; j < 4; ++j) acc[i][j] = (f32x4){0.f, 0.f, 0.f, 0.f};

  // prologue: full K-tile 0 + {Am0,Bn0} of K-tile 1; confirm tile 0, leave 2 half-tiles in flight
  stgA(aBuf0, 0, 0); stgB(bBuf0, 0, 0); stgB(bBuf0, 1, 0); stgA(aBuf0, 1, 0);
  stgA(aBuf1, 0, 1); stgB(bBuf1, 0, 1);
  if constexpr (BM == 256) asm volatile("s_waitcnt vmcnt(4)" ::: "memory");
  else                     asm volatile("s_waitcnt vmcnt(3)" ::: "memory");
  FBAR();

  int NT = Kd >> 6;
  bf16x8 af[MH][2], bfr0[2][2], bfr1[2][2];
  for (int t = 0; t < NT; ++t) {
    unsigned short* aCur = (t & 1) ? aBuf1 : aBuf0;
    unsigned short* bCur = (t & 1) ? bBuf1 : bBuf0;
    unsigned short* aNxt = (t & 1) ? aBuf0 : aBuf1;
    unsigned short* bNxt = (t & 1) ? bBuf0 : bBuf1;

    // ---- P1: consume (m0,n0); prefetch B-n1(t+1) ----
#pragma unroll
    for (int i = 0; i < MH; ++i) { af[i][0] = rdA(aCur, i, 0); af[i][1] = rdA(aCur, i, 1); }
#pragma unroll
    for (int j = 0; j < 2; ++j) { bfr0[j][0] = rdB(bCur, j, 0); bfr0[j][1] = rdB(bCur, j, 1); }
    if (t + 1 < NT) stgB(bNxt, 1, t + 1);
    FBAR();
    __builtin_amdgcn_s_setprio(1);
#pragma unroll
    for (int kk = 0; kk < 2; ++kk)
#pragma unroll
      for (int i = 0; i < MH; ++i)
#pragma unroll
        for (int j = 0; j < 2; ++j)
          acc[i][j] = __builtin_amdgcn_mfma_f32_16x16x32_bf16(af[i][kk], bfr0[j][kk], acc[i][j], 0, 0, 0);
    __builtin_amdgcn_s_setprio(0);

    // ---- P2: consume (m0,n1); prefetch A-m1(t+1) ----
#pragma unroll
    for (int j = 0; j < 2; ++j) { bfr1[j][0] = rdB(bCur, j + 2, 0); bfr1[j][1] = rdB(bCur, j + 2, 1); }
    if (t + 1 < NT) stgA(aNxt, 1, t + 1);
    FBAR();
    __builtin_amdgcn_s_setprio(1);
#pragma unroll
    for (int kk = 0; kk < 2; ++kk)
#pragma unroll
      for (int i = 0; i < MH; ++i)
#pragma unroll
        for (int j = 0; j < 2; ++j)
          acc[i][j + 2] = __builtin_amdgcn_mfma_f32_16x16x32_bf16(af[i][kk], bfr1[j][kk], acc[i][j + 2], 0, 0, 0);
    __builtin_amdgcn_s_setprio(0);

    // ---- P3: consume (m1,n0); prefetch A-m0(t+2) into current buffer ----
#pragma unroll
    for (int i = 0; i < MH; ++i) { af[i][0] = rdA(aCur, MH + i, 0); af[i][1] = rdA(aCur, MH + i, 1); }
    if (t + 2 < NT) stgA(aCur, 0, t + 2);
    FBAR();
    __builtin_amdgcn_s_setprio(1);
#pragma unroll
    for (int kk = 0; kk < 2; ++kk)
#pragma unroll
      for (int i = 0; i < MH; ++i)
#pragma unroll
        for (int j = 0; j < 2; ++j)
          acc[MH + i][j] = __builtin_amdgcn_mfma_f32_16x16x32_bf16(af[i][kk], bfr0[j][kk], acc[MH + i][j], 0, 0, 0);
    __builtin_amdgcn_s_setprio(0);

    // ---- P4: consume (m1,n1); prefetch B-n0(t+2); counted vmcnt (never 0 mid-loop) ----
    if (t + 2 < NT) {
      stgB(bCur, 0, t + 2);
      if constexpr (BM == 256) asm volatile("s_waitcnt vmcnt(4)" ::: "memory");
      else                     asm volatile("s_waitcnt vmcnt(3)" ::: "memory");
    } else {
      asm volatile("s_waitcnt vmcnt(0)" ::: "memory");
    }
    FBAR();
    __builtin_amdgcn_s_setprio(1);
#pragma unroll
    for (int kk = 0; kk < 2; ++kk)
#pragma unroll
      for (int i = 0; i < MH; ++i)
#pragma unroll
        for (int j = 0; j < 2; ++j)
          acc[MH + i][j + 2] = __builtin_amdgcn_mfma_f32_16x16x32_bf16(af[i][kk], bfr1[j][kk], acc[MH + i][j + 2], 0, 0, 0);
    __builtin_amdgcn_s_setprio(0);
  }

  // epilogue: C/D layout col=lane&15, row=quad*4+reg
  float* outf = (float*)out_;
  unsigned short* outb = (unsigned short*)out_;
  const float* addf = (const float*)add_;
  const unsigned short* addb = (const unsigned short*)add_;
  long orow = rowBase + wm * (BM / 2);
  long ocol = colBase + wn * 64 + l16;
#pragma unroll
  for (int i = 0; i < MR; ++i)
#pragma unroll
    for (int j = 0; j < 4; ++j)
#pragma unroll
      for (int rr = 0; rr < 4; ++rr) {
        long row = orow + i * 16 + quad * 4 + rr;
        long col = ocol + j * 16;
        long idx = row * (long)ldc + col;
        float v = acc[i][j][rr];
        if (MODE == 0) {
          outb[idx] = f2bf(v);
        } else if (MODE == 1) {
          v += (ADD_F32 ? addf[idx] : bf2f(addb[idx]));
          if (OUT_F32) outf[idx] = v; else outb[idx] = f2bf(v);
        } else {  // MODE 2: gating fuse, out currently holds up-projection
          outb[idx] = f2bf(gelu_f(v) * bf2f(outb[idx]));
        }
      }
}

// ---------------- RoPE on q (cols 0..2047, *H^-0.5) and k (cols 2048..3071), bf16 in place ----
__global__ __launch_bounds__(256) void rope_kernel(unsigned short* __restrict__ qkv,
                                                   const int* __restrict__ pos) {
  int gid = blockIdx.x * 256 + threadIdx.x;  // (row*24 + head)*64 + hp
  int hp = gid & 63;
  int rh = gid >> 6;
  int row = rh / 24;
  int head = rh - row * 24;
  float p = (float)pos[row];
  long cb; float sc;
  if (head < 16) { cb = (long)head * 128; sc = 0.08838834764831845f; }  // H^-0.5
  else { cb = 2048 + (long)(head - 16) * 128; sc = 1.f; }
  unsigned short* ptr = qkv + (long)row * 4096 + cb;
  float inv = exp2f(-(float)hp * (13.287712379549449f / 64.f));  // 10000^(-hp/64)
  float ang = p * inv;
  float s = sinf(ang), c = cosf(ang);
  float x1 = bf2f(ptr[hp]), x2 = bf2f(ptr[hp + 64]);
  ptr[hp]      = f2bf((x1 * c - x2 * s) * sc);
  ptr[hp + 64] = f2bf((x2 * c + x1 * s) * sc);
}

// ---------------- Flash attention: block = (qt, n, b), 64 Q-rows, 64-wide KV steps ----------------
__global__ __launch_bounds__(256, 2) void attn_kernel(const unsigned short* __restrict__ qkv,
                                                      const unsigned short* __restrict__ vT,
                                                      unsigned short* __restrict__ enc) {
  extern __shared__ char smem[];
  unsigned short* sK = (unsigned short*)smem;                     // 16384 B
  unsigned short* sVT = sK + 64 * 128;                            // 16384 B
  float* sS = (float*)(smem + 32768);                             // 64*66*4 = 16896 B
  unsigned short* sP = (unsigned short*)(smem + 32768 + 16896);   // 64*72*2 = 9216 B
  float* sM = (float*)(smem + 32768 + 16896 + 9216);
  float* sL = sM + 64;
  float* sAl = sL + 64;                                           // total 59648 B

  int qt = blockIdx.x, n = blockIdx.y, b = blockIdx.z;
  int tid = threadIdx.x, lane = tid & 63, w = tid >> 6;
  int quad = lane >> 4, l16 = lane & 15;
  int kh = n >> 1;
  long rowQ = (long)b * 2048 + (long)qt * 64;

  bf16x8 qf[4];
  {
    const unsigned short* qp = qkv + (rowQ + w * 16 + l16) * 4096 + n * 128 + quad * 8;
#pragma unroll
    for (int ks = 0; ks < 4; ++ks) qf[ks] = *(const bf16x8*)(qp + ks * 32);
  }
  if (tid < 64) { sM[tid] = -1e30f; sL[tid] = 0.f; }
  f32x4 oacc[8];
#pragma unroll
  for (int t = 0; t < 8; ++t) oacc[t] = (f32x4){0.f, 0.f, 0.f, 0.f};

  int srow = tid >> 2, cg = tid & 3;

  for (int st = 0; st <= qt; ++st) {
    __syncthreads();  // (1) prev-iter LDS consumers done (also covers sM/sL init)
#pragma unroll
    for (int it = 0; it < 4; ++it) {  // stage K tile, chunk-swizzled
      int idx = it * 256 + tid;
      int r = idx >> 4, c = idx & 15;
      bf16x8 kv8 = *(const bf16x8*)(qkv + ((long)b * 2048 + st * 64 + r) * 4096 + 2048 + kh * 128 + c * 8);
      *(bf16x8*)(sK + r * 128 + ((c ^ (r & 7)) * 8)) = kv8;
    }
#pragma unroll
    for (int it = 0; it < 4; ++it) {  // stage V^T tile, chunk-swizzled
      int idx = it * 256 + tid;
      int h = idx >> 3, c = idx & 7;
      bf16x8 vv8 = *(const bf16x8*)(vT + ((long)(b * 8 + kh) * 128 + h) * 2048 + st * 64 + c * 8);
      *(bf16x8*)(sVT + h * 64 + ((c ^ (h & 7)) * 8)) = vv8;
    }
    __syncthreads();  // (2) staging visible

    f32x4 sacc[4];
#pragma unroll
    for (int nt = 0; nt < 4; ++nt) sacc[nt] = (f32x4){0.f, 0.f, 0.f, 0.f};
#pragma unroll
    for (int ks = 0; ks < 4; ++ks)
#pragma unroll
      for (int nt = 0; nt < 4; ++nt) {
        int r = nt * 16 + l16;
        bf16x8 kf = *(const bf16x8*)(sK + r * 128 + (((ks * 4 + quad) ^ (r & 7)) * 8));
        sacc[nt] = __builtin_amdgcn_mfma_f32_16x16x32_bf16(qf[ks], kf, sacc[nt], 0, 0, 0);
      }
#pragma unroll
    for (int nt = 0; nt < 4; ++nt)
#pragma unroll
      for (int r = 0; r < 4; ++r)
        sS[(w * 16 + quad * 4 + r) * 66 + nt * 16 + l16] = sacc[nt][r];
    __syncthreads();  // (3) S visible

    // online softmax (4 threads per row, 16 cols each)
    float vals[16];
    int tglob = qt * 64 + srow;
    float mx = -1e30f;
#pragma unroll
    for (int j = 0; j < 16; ++j) {
      int col = cg * 16 + j;
      float v = sS[srow * 66 + col];
      if (st * 64 + col > tglob) v = -1e30f;  // causal
      vals[j] = v;
      mx = fmaxf(mx, v);
    }
    mx = fmaxf(mx, __shfl_xor(mx, 1));
    mx = fmaxf(mx, __shfl_xor(mx, 2));
    float m_old = sM[srow], l_old = sL[srow];
    float m_new = fmaxf(m_old, mx);
    float alpha = __expf(m_old - m_new);
    float sum = 0.f;
#pragma unroll
    for (int j = 0; j < 16; ++j) { vals[j] = __expf(vals[j] - m_new); sum += vals[j]; }
    sum += __shfl_xor(sum, 1);
    sum += __shfl_xor(sum, 2);
    float l_new = alpha * l_old + sum;
    __syncthreads();  // (4)

#pragma unroll
    for (int jj = 0; jj < 8; ++jj) {  // write P (bf16 pairs, separate region)
      unsigned int pk = (unsigned int)f2bf(vals[2 * jj]) | ((unsigned int)f2bf(vals[2 * jj + 1]) << 16);
      *(unsigned int*)(sP + srow * 72 + cg * 16 + jj * 2) = pk;
    }
    if (cg == 0) { sM[srow] = m_new; sL[srow] = l_new; sAl[srow] = alpha; }
    __syncthreads();  // (5) P/alpha visible

#pragma unroll
    for (int r = 0; r < 4; ++r) {  // rescale O
      float al = sAl[w * 16 + quad * 4 + r];
#pragma unroll
      for (int nt = 0; nt < 8; ++nt) oacc[nt][r] *= al;
    }
#pragma unroll
    for (int ks = 0; ks < 2; ++ks) {  // O += P*V
      bf16x8 pf = *(const bf16x8*)(sP + (w * 16 + l16) * 72 + ks * 32 + quad * 8);
#pragma unroll
      for (int nt = 0; nt < 8; ++nt) {
        int hh = nt * 16 + l16;
        bf16x8 vf = *(const bf16x8*)(sVT + hh * 64 + (((ks * 4 + quad) ^ (hh & 7)) * 8));
        oacc[nt] = __builtin_amdgcn_mfma_f32_16x16x32_bf16(pf, vf, oacc[nt], 0, 0, 0);
      }
    }
  }

#pragma unroll
  for (int r = 0; r < 4; ++r) {  // O /= l, write enc (B,T,N,H) bf16
    float invl = 1.f / sL[w * 16 + quad * 4 + r];
    long trow = rowQ + w * 16 + quad * 4 + r;
#pragma unroll
    for (int nt = 0; nt < 8; ++nt)
      enc[trow * 2048 + n * 128 + nt * 16 + l16] = f2bf(oacc[nt][r] * invl);
  }
}

extern "C" void kernel_launch(void* const* d_in, const int* in_sizes, int n_in,
                              void* d_out, int out_size, void* d_ws, size_t ws_size,
                              hipStream_t stream) {
  const float* x = (const float*)d_in[0];
  const int* positions = (const int*)d_in[1];
  // d_in[2] = attn_mask: deterministic causal tril, not read
  const float* wq = (const float*)d_in[3];
  const float* wkv = (const float*)d_in[4];
  const float* wav = (const float*)d_in[5];
  const float* s_attn = (const float*)d_in[6];
  const float* s_ffw = (const float*)d_in[7];
  const float* wg = (const float*)d_in[8];
  const float* wl = (const float*)d_in[9];
  float* outp = (float*)d_out;

  char* ws = (char*)d_ws;
  size_t o = 0;
  unsigned short* XN = (unsigned short*)(ws + o);    o += (size_t)4096 * 2048 * 2;   // 16 MiB
  unsigned short* WQKVT = (unsigned short*)(ws + o); o += (size_t)4096 * 2048 * 2;   // 16 MiB
  unsigned short* WAVT = (unsigned short*)(ws + o);  o += (size_t)2048 * 2048 * 2;   // 8 MiB
  unsigned short* WGT = (unsigned short*)(ws + o);   o += (size_t)8192 * 2048 * 2;   // 32 MiB (time-shared)
  unsigned short* QKV = (unsigned short*)(ws + o);   o += (size_t)4096 * 4096 * 2;   // 32 MiB
  unsigned short* VTb = (unsigned short*)(ws + o);   o += (size_t)16 * 128 * 2048 * 2; // 8 MiB
  unsigned short* ACT = (unsigned short*)(ws + o);   o += (size_t)4096 * 8192 * 2;   // 64 MiB
  // total 176 MiB. aliases (lifetimes disjoint):
  unsigned short* ENC = WQKVT;  // WQKVT dead after qkv GEMM
  unsigned short* RES = QKV;    // QKV dead after attention
  unsigned short* HB = XN;      // XN dead after qkv GEMM

  dim3 b256(256), bT(32, 8);

  // 1. xn = rmsnorm(x_fp32, scale_pre_attn) -> bf16
  rmsnorm_kernel<1><<<4096, b256, 0, stream>>>(x, s_attn, XN);

  // 2. transpose+cast attention weights
  transpose_cast_kernel<<<dim3(4, 64, 16), bT, 0, stream>>>(wq, WQKVT, 2048, 128, 262144L, 262144L);
  transpose_cast_kernel<<<dim3(4, 64, 8), bT, 0, stream>>>(wkv, WQKVT + (size_t)2048 * 2048, 2048, 128, 262144L, 262144L);
  transpose_cast_kernel<<<dim3(4, 64, 8), bT, 0, stream>>>(wkv + (size_t)8 * 262144, WQKVT + (size_t)3072 * 2048, 2048, 128, 262144L, 262144L);
  transpose_cast_kernel<<<dim3(64, 64, 1), bT, 0, stream>>>(wav, WAVT, 2048, 2048, 0L, 0L);

  // 3. qkv = xn @ [Wq|Wk|Wv]  (4096 x 4096, bf16)
  gemm8p<256, 0, 0, 0><<<256, 512, 0, stream>>>(XN, WQKVT, 2048, 4096, 16, QKV, nullptr);

  // 4. v -> vT
  vtrans_kernel<<<dim3(64, 4, 16), bT, 0, stream>>>(QKV, VTb);

  // 5. RoPE on q (scaled) and k, in place
  rope_kernel<<<24576, b256, 0, stream>>>(QKV, positions);

  // 6. attention -> enc (B,T,N,H) bf16
  attn_kernel<<<dim3(32, 16, 2), b256, 59648, stream>>>(QKV, VTb, ENC);

  // 7. resid = x_fp32 + enc @ Wav  -> bf16 RES
  gemm8p<128, 1, 0, 1><<<256, 512, 0, stream>>>(ENC, WAVT, 2048, 2048, 8, RES, x);

  // 8. h = rmsnorm(resid_bf16, scale_pre_ffw) -> bf16
  rmsnorm_kernel<0><<<4096, b256, 0, stream>>>(RES, s_ffw, HB);

  // 9. gating in two F-halves (WGT time-shared: Wg0T-half | Wg1T-half, 16 MiB each).
  //    Un-fused: up-pass writes ACT, gate-pass RMWs gelu(g)*u in its epilogue.
  for (int half = 0; half < 2; ++half) {
    long f0 = (long)half * 4096;
    transpose_cast_kernel<<<dim3(128, 64, 1), bT, 0, stream>>>(wg + f0, WGT, 2048, 8192, 0L, 0L);
    transpose_cast_kernel<<<dim3(128, 64, 1), bT, 0, stream>>>(wg + (size_t)2048 * 8192 + f0,
                                                               WGT + (size_t)4096 * 2048, 2048, 8192, 0L, 0L);
    gemm8p<256, 0, 0, 0><<<256, 512, 0, stream>>>(HB, WGT + (size_t)4096 * 2048, 2048, 8192, 16, ACT + f0, nullptr);
    gemm8p<256, 2, 0, 0><<<256, 512, 0, stream>>>(HB, WGT, 2048, 8192, 16, ACT + f0, nullptr);
  }

  // 10. out_fp32 = resid + act @ Wlin (WGT reused for Wlin^T)
  transpose_cast_kernel<<<dim3(64, 256, 1), bT, 0, stream>>>(wl, WGT, 8192, 2048, 0L, 0L);
  gemm8p<128, 1, 1, 0><<<256, 512, 0, stream>>>(ACT, WGT, 8192, 2048, 8, outp, RES);
}